// Round 1
// baseline (879.001 us; speedup 1.0000x reference)
//
#include <hip/hip_runtime.h>
#include <math.h>

#define N_NODES 100000
#define N_EDGES 1600000

// ---------------- CSR build ----------------

__global__ void k_zero_int(int* __restrict__ p, int n) {
    int i = blockIdx.x * blockDim.x + threadIdx.x;
    if (i < n) p[i] = 0;
}

__global__ void k_count(const int* __restrict__ dstv, int* __restrict__ cnt) {
    int e = blockIdx.x * blockDim.x + threadIdx.x;
    if (e < N_EDGES) atomicAdd(&cnt[dstv[e]], 1);
}

__global__ void k_dinv(const int* __restrict__ cnt, float* __restrict__ dinv) {
    int i = blockIdx.x * blockDim.x + threadIdx.x;
    if (i < N_NODES) dinv[i] = rsqrtf((float)(cnt[i] + 1));  // +1 self-loop
}

__global__ void k_scan1(const int* __restrict__ cnt, int* __restrict__ rowptr,
                        int* __restrict__ bsums) {
    __shared__ int s[1024];
    int tid = threadIdx.x;
    int i = blockIdx.x * 1024 + tid;
    int v = (i < N_NODES) ? cnt[i] : 0;
    int x = v;
    s[tid] = x;
    __syncthreads();
    for (int d = 1; d < 1024; d <<= 1) {
        int t = (tid >= d) ? s[tid - d] : 0;
        __syncthreads();
        x += t;
        s[tid] = x;
        __syncthreads();
    }
    if (i < N_NODES) rowptr[i] = x - v;  // exclusive prefix
    if (tid == 1023) bsums[blockIdx.x] = x;
}

__global__ void k_scan2(int* __restrict__ bsums, int nb) {
    __shared__ int s[128];
    int tid = threadIdx.x;
    int v = (tid < nb) ? bsums[tid] : 0;
    int x = v;
    s[tid] = x;
    __syncthreads();
    for (int d = 1; d < 128; d <<= 1) {
        int t = (tid >= d) ? s[tid - d] : 0;
        __syncthreads();
        x += t;
        s[tid] = x;
        __syncthreads();
    }
    if (tid < nb) bsums[tid] = x - v;  // exclusive
}

__global__ void k_scan3(int* __restrict__ rowptr, const int* __restrict__ bsums,
                        int* __restrict__ cursor) {
    int i = blockIdx.x * 1024 + threadIdx.x;
    if (i < N_NODES) {
        rowptr[i] += bsums[blockIdx.x];
        cursor[i] = 0;  // reset for fill pass
    }
    if (i == 0) rowptr[N_NODES] = N_EDGES;
}

__global__ void k_fill(const int* __restrict__ srcv, const int* __restrict__ dstv,
                       const int* __restrict__ rowptr, int* __restrict__ cursor,
                       int* __restrict__ colidx) {
    int e = blockIdx.x * blockDim.x + threadIdx.x;
    if (e < N_EDGES) {
        int d = dstv[e];
        int pos = atomicAdd(&cursor[d], 1);
        colidx[rowptr[d] + pos] = srcv[e];
    }
}

// ---------------- GEMM: h'[r,:] = dinv[r] * (A[r,:] @ W) ----------------
// K fixed at 128. W staged in LDS (zero-padded to NC cols). A read from global
// (same-address broadcast across lanes -> L1-served). 4col x 8row register tile.

template <int NC>
__launch_bounds__(256)
__global__ void k_gemm_scaled(const float* __restrict__ A, const float* __restrict__ W,
                              const float* __restrict__ dinv, float* __restrict__ out,
                              int ncols) {
    constexpr int CG = NC / 4;       // col groups of 4
    constexpr int RG = 256 / CG;     // row groups of 8
    constexpr int ROWS = RG * 8;     // rows per block
    __shared__ float Ws[128 * NC];

    const int tid = threadIdx.x;
    for (int idx = tid; idx < 128 * NC; idx += 256) {
        int k = idx / NC, c = idx % NC;
        Ws[idx] = (c < ncols) ? W[k * ncols + c] : 0.f;
    }
    __syncthreads();

    const int cg = tid % CG;
    const int rg = tid / CG;
    const int col0 = cg * 4;
    const int rowbase = blockIdx.x * ROWS + rg * 8;

    float acc[8][4];
#pragma unroll
    for (int i = 0; i < 8; i++)
#pragma unroll
        for (int j = 0; j < 4; j++) acc[i][j] = 0.f;

    int rclamp[8];
#pragma unroll
    for (int i = 0; i < 8; i++) rclamp[i] = min(rowbase + i, N_NODES - 1);

    for (int k = 0; k < 128; k += 4) {
        float4 a[8];
#pragma unroll
        for (int i = 0; i < 8; i++)
            a[i] = *(const float4*)(A + (size_t)rclamp[i] * 128 + k);
        float4 w0 = *(const float4*)&Ws[(k + 0) * NC + col0];
        float4 w1 = *(const float4*)&Ws[(k + 1) * NC + col0];
        float4 w2 = *(const float4*)&Ws[(k + 2) * NC + col0];
        float4 w3 = *(const float4*)&Ws[(k + 3) * NC + col0];
#pragma unroll
        for (int i = 0; i < 8; i++) {
            float ax = a[i].x, ay = a[i].y, az = a[i].z, aw = a[i].w;
            acc[i][0] = fmaf(ax, w0.x, acc[i][0]); acc[i][0] = fmaf(ay, w1.x, acc[i][0]);
            acc[i][0] = fmaf(az, w2.x, acc[i][0]); acc[i][0] = fmaf(aw, w3.x, acc[i][0]);
            acc[i][1] = fmaf(ax, w0.y, acc[i][1]); acc[i][1] = fmaf(ay, w1.y, acc[i][1]);
            acc[i][1] = fmaf(az, w2.y, acc[i][1]); acc[i][1] = fmaf(aw, w3.y, acc[i][1]);
            acc[i][2] = fmaf(ax, w0.z, acc[i][2]); acc[i][2] = fmaf(ay, w1.z, acc[i][2]);
            acc[i][2] = fmaf(az, w2.z, acc[i][2]); acc[i][2] = fmaf(aw, w3.z, acc[i][2]);
            acc[i][3] = fmaf(ax, w0.w, acc[i][3]); acc[i][3] = fmaf(ay, w1.w, acc[i][3]);
            acc[i][3] = fmaf(az, w2.w, acc[i][3]); acc[i][3] = fmaf(aw, w3.w, acc[i][3]);
        }
    }

    if (col0 < ncols) {
#pragma unroll
        for (int i = 0; i < 8; i++) {
            int r = rowbase + i;
            if (r < N_NODES) {
                float dv = dinv[r];
                float4 o = make_float4(acc[i][0] * dv, acc[i][1] * dv,
                                       acc[i][2] * dv, acc[i][3] * dv);
                *(float4*)(out + (size_t)r * ncols + col0) = o;
            }
        }
    }
}

// ---------------- Aggregation (F=128): one wave per row, float2 per lane ----------------

template <bool RELU>
__launch_bounds__(256)
__global__ void k_aggregate128(const float* __restrict__ hp, const int* __restrict__ rowptr,
                               const int* __restrict__ colidx, const float* __restrict__ dinv,
                               const float* __restrict__ bias, float* __restrict__ out) {
    const int r = (blockIdx.x * blockDim.x + threadIdx.x) >> 6;
    const int lane = threadIdx.x & 63;
    if (r >= N_NODES) return;
    const float2* hp2 = (const float2*)hp;

    float2 acc = hp2[(size_t)r * 64 + lane];  // self-loop term
    int e = rowptr[r];
    const int e1 = rowptr[r + 1];
    for (; e + 4 <= e1; e += 4) {
        int s0 = colidx[e], s1 = colidx[e + 1], s2 = colidx[e + 2], s3 = colidx[e + 3];
        float2 v0 = hp2[(size_t)s0 * 64 + lane];
        float2 v1 = hp2[(size_t)s1 * 64 + lane];
        float2 v2 = hp2[(size_t)s2 * 64 + lane];
        float2 v3 = hp2[(size_t)s3 * 64 + lane];
        acc.x += (v0.x + v1.x) + (v2.x + v3.x);
        acc.y += (v0.y + v1.y) + (v2.y + v3.y);
    }
    for (; e < e1; e++) {
        int s = colidx[e];
        float2 v = hp2[(size_t)s * 64 + lane];
        acc.x += v.x;
        acc.y += v.y;
    }
    float dv = dinv[r];
    float2 b = ((const float2*)bias)[lane];
    float ox = fmaf(dv, acc.x, b.x);
    float oy = fmaf(dv, acc.y, b.y);
    if (RELU) {
        ox = fmaxf(ox, 0.f);
        oy = fmaxf(oy, 0.f);
    }
    ((float2*)out)[(size_t)r * 64 + lane] = make_float2(ox, oy);
}

// ---------------- Final aggregation (F=40) + fused log_softmax ----------------

__launch_bounds__(256)
__global__ void k_aggregate_out(const float* __restrict__ hp, const int* __restrict__ rowptr,
                                const int* __restrict__ colidx, const float* __restrict__ dinv,
                                float* __restrict__ out) {
    const int r = (blockIdx.x * blockDim.x + threadIdx.x) >> 6;
    const int lane = threadIdx.x & 63;
    if (r >= N_NODES) return;
    const bool act = lane < 40;

    float acc = act ? hp[(size_t)r * 40 + lane] : 0.f;  // self-loop
    int e = rowptr[r];
    const int e1 = rowptr[r + 1];
    for (; e + 4 <= e1; e += 4) {
        int s0 = colidx[e], s1 = colidx[e + 1], s2 = colidx[e + 2], s3 = colidx[e + 3];
        if (act) {
            float v0 = hp[(size_t)s0 * 40 + lane];
            float v1 = hp[(size_t)s1 * 40 + lane];
            float v2 = hp[(size_t)s2 * 40 + lane];
            float v3 = hp[(size_t)s3 * 40 + lane];
            acc += (v0 + v1) + (v2 + v3);
        }
    }
    for (; e < e1; e++) {
        int s = colidx[e];
        if (act) acc += hp[(size_t)s * 40 + lane];
    }
    float z = act ? dinv[r] * acc : -INFINITY;
    // 64-lane max reduce
    float m = z;
    for (int off = 32; off; off >>= 1) m = fmaxf(m, __shfl_xor(m, off));
    float ex = act ? __expf(z - m) : 0.f;
    float se = ex;
    for (int off = 32; off; off >>= 1) se += __shfl_xor(se, off);
    if (act) out[(size_t)r * 40 + lane] = z - m - __logf(se);
}

// ---------------- launch ----------------

extern "C" void kernel_launch(void* const* d_in, const int* in_sizes, int n_in,
                              void* d_out, int out_size, void* d_ws, size_t ws_size,
                              hipStream_t stream) {
    const float* x     = (const float*)d_in[0];
    const int*   ei    = (const int*)d_in[1];  // [2, E] int32
    const float* W_in  = (const float*)d_in[2];
    const float* b_in  = (const float*)d_in[3];
    const float* W_mid = (const float*)d_in[4];
    const float* b_mid = (const float*)d_in[5];
    const float* W_out = (const float*)d_in[6];
    float* out = (float*)d_out;

    const int* srcv = ei;
    const int* dstv = ei + N_EDGES;

    char* w = (char*)d_ws;
    float* dinv  = (float*)(w);                       // N floats
    int* rowptr  = (int*)(w + (1ull << 20));          // N+1 ints
    int* cursor  = (int*)(w + (2ull << 20));          // N ints (counts, then cursors)
    int* bsums   = (int*)(w + (3ull << 20));          // 98 ints
    int* colidx  = (int*)(w + (4ull << 20));          // E ints (6.4 MB)
    float* bufA  = (float*)(w + (12ull << 20));       // N*128 floats (51.2 MB)
    float* bufB  = (float*)(w + (64ull << 20));       // N*128 floats (51.2 MB)

    const int NB_N = (N_NODES + 255) / 256;
    const int NB_E = (N_EDGES + 255) / 256;
    const int NB_SCAN = (N_NODES + 1023) / 1024;  // 98

    // CSR + dinv
    k_zero_int<<<NB_N, 256, 0, stream>>>(cursor, N_NODES);
    k_count<<<NB_E, 256, 0, stream>>>(dstv, cursor);
    k_dinv<<<NB_N, 256, 0, stream>>>(cursor, dinv);
    k_scan1<<<NB_SCAN, 1024, 0, stream>>>(cursor, rowptr, bsums);
    k_scan2<<<1, 128, 0, stream>>>(bsums, NB_SCAN);
    k_scan3<<<NB_SCAN, 1024, 0, stream>>>(rowptr, bsums, cursor);
    k_fill<<<NB_E, 256, 0, stream>>>(srcv, dstv, rowptr, cursor, colidx);

    const int AGG_BLOCKS = N_NODES / 4;  // 4 waves/block, 1 wave per row

    // Layer 1: h' = dinv*(x@W_in) -> bufA ; aggregate+bias+relu -> bufB
    k_gemm_scaled<128><<<(N_NODES + 63) / 64, 256, 0, stream>>>(x, W_in, dinv, bufA, 128);
    k_aggregate128<true><<<AGG_BLOCKS, 256, 0, stream>>>(bufA, rowptr, colidx, dinv, b_in, bufB);

    // Layer 2
    k_gemm_scaled<128><<<(N_NODES + 63) / 64, 256, 0, stream>>>(bufB, W_mid, dinv, bufA, 128);
    k_aggregate128<true><<<AGG_BLOCKS, 256, 0, stream>>>(bufA, rowptr, colidx, dinv, b_mid, bufB);

    // Layer 3 (40 cols, no bias) + fused log_softmax
    k_gemm_scaled<64><<<(N_NODES + 127) / 128, 256, 0, stream>>>(bufB, W_out, dinv, bufA, 40);
    k_aggregate_out<<<AGG_BLOCKS, 256, 0, stream>>>(bufA, rowptr, colidx, dinv, out);
}

// Round 2
// 619.400 us; speedup vs baseline: 1.4191x; 1.4191x over previous
//
#include <hip/hip_runtime.h>
#include <math.h>

#define N_NODES 100000
#define N_EDGES 1600000

typedef __attribute__((ext_vector_type(8))) short bf16x8;
typedef __attribute__((ext_vector_type(4))) float f32x4;
typedef __attribute__((ext_vector_type(2))) _Float16 h2v;

__device__ inline unsigned short f2bf_rn(float v) {
    unsigned int u = __builtin_bit_cast(unsigned int, v);
    unsigned int r = u + 0x7fffu + ((u >> 16) & 1u);
    return (unsigned short)(r >> 16);
}
__device__ inline float bf2f(unsigned short h) {
    unsigned int u = (unsigned int)h << 16;
    return __builtin_bit_cast(float, u);
}
__device__ inline void split_bf(float v, unsigned short& hi, unsigned short& lo) {
    hi = f2bf_rn(v);
    lo = f2bf_rn(v - bf2f(hi));
}

// ---------------- CSR build ----------------

__global__ void k_zero_int(int* __restrict__ p, int n) {
    int i = blockIdx.x * blockDim.x + threadIdx.x;
    if (i < n) p[i] = 0;
}

__global__ void k_count(const int* __restrict__ dstv, int* __restrict__ cnt) {
    int e = blockIdx.x * blockDim.x + threadIdx.x;
    if (e < N_EDGES) atomicAdd(&cnt[dstv[e]], 1);
}

__global__ void k_dinv(const int* __restrict__ cnt, float* __restrict__ dinv) {
    int i = blockIdx.x * blockDim.x + threadIdx.x;
    if (i < N_NODES) dinv[i] = rsqrtf((float)(cnt[i] + 1));  // +1 self-loop
}

__global__ void k_scan1(const int* __restrict__ cnt, int* __restrict__ rowptr,
                        int* __restrict__ bsums) {
    __shared__ int s[1024];
    int tid = threadIdx.x;
    int i = blockIdx.x * 1024 + tid;
    int v = (i < N_NODES) ? cnt[i] : 0;
    int x = v;
    s[tid] = x;
    __syncthreads();
    for (int d = 1; d < 1024; d <<= 1) {
        int t = (tid >= d) ? s[tid - d] : 0;
        __syncthreads();
        x += t;
        s[tid] = x;
        __syncthreads();
    }
    if (i < N_NODES) rowptr[i] = x - v;  // exclusive prefix
    if (tid == 1023) bsums[blockIdx.x] = x;
}

__global__ void k_scan2(int* __restrict__ bsums, int nb) {
    __shared__ int s[128];
    int tid = threadIdx.x;
    int v = (tid < nb) ? bsums[tid] : 0;
    int x = v;
    s[tid] = x;
    __syncthreads();
    for (int d = 1; d < 128; d <<= 1) {
        int t = (tid >= d) ? s[tid - d] : 0;
        __syncthreads();
        x += t;
        s[tid] = x;
        __syncthreads();
    }
    if (tid < nb) bsums[tid] = x - v;  // exclusive
}

__global__ void k_scan3(int* __restrict__ rowptr, const int* __restrict__ bsums,
                        int* __restrict__ cursor) {
    int i = blockIdx.x * 1024 + threadIdx.x;
    if (i < N_NODES) {
        rowptr[i] += bsums[blockIdx.x];
        cursor[i] = 0;  // reset for fill pass
    }
    if (i == 0) rowptr[N_NODES] = N_EDGES;
}

__global__ void k_fill(const int* __restrict__ srcv, const int* __restrict__ dstv,
                       const int* __restrict__ rowptr, int* __restrict__ cursor,
                       int* __restrict__ colidx) {
    int e = blockIdx.x * blockDim.x + threadIdx.x;
    if (e < N_EDGES) {
        int d = dstv[e];
        int pos = atomicAdd(&cursor[d], 1);
        colidx[rowptr[d] + pos] = srcv[e];
    }
}

// ---------------- input / weight conversion ----------------

// x (fp32, N*128) -> hi/lo bf16 planes
__global__ void k_split_x(const float* __restrict__ x, unsigned short* __restrict__ phi,
                          unsigned short* __restrict__ plo) {
    int i = blockIdx.x * blockDim.x + threadIdx.x;
    int base = i * 4;
    if (base >= N_NODES * 128) return;
    float4 v = *(const float4*)(x + base);
    ushort4 h, l;
    split_bf(v.x, h.x, l.x);
    split_bf(v.y, h.y, l.y);
    split_bf(v.z, h.z, l.z);
    split_bf(v.w, h.w, l.w);
    *(ushort4*)(phi + base) = h;
    *(ushort4*)(plo + base) = l;
}

// W [128 x ncols] fp32 -> Wt hi/lo [ntcols x 128] bf16 (transposed, zero-padded cols)
__global__ void k_wprep(const float* __restrict__ W, int ncols, int ntcols,
                        unsigned short* __restrict__ Wthi, unsigned short* __restrict__ Wtlo) {
    int idx = blockIdx.x * blockDim.x + threadIdx.x;
    if (idx >= ntcols * 128) return;
    int n = idx / 128, k = idx % 128;
    float v = (n < ncols) ? W[k * ncols + n] : 0.f;
    unsigned short hi, lo;
    split_bf(v, hi, lo);
    Wthi[n * 128 + k] = hi;
    Wtlo[n * 128 + k] = lo;
}

// ---------------- MFMA GEMM: h'[r,c] = dinv[r] * sum_k A[r,k] W[k,c], NC=128 ----------------
// A = Ahi + Alo (split bf16), product = Ahi*Whi + Ahi*Wlo + Alo*Whi (fp32-grade).
// Block: 256 thr = 4 waves; block covers 32 rows; wave wi covers cols [wi*32, wi*32+32).
// B fragments register-resident from pre-transposed Wt[n][k]. No LDS, no barriers.

__launch_bounds__(256)
__global__ void k_gemm128(const unsigned short* __restrict__ Ahi, const unsigned short* __restrict__ Alo,
                          const unsigned short* __restrict__ Wthi, const unsigned short* __restrict__ Wtlo,
                          const float* __restrict__ dinv, _Float16* __restrict__ out) {
    const int lane = threadIdx.x & 63;
    const int wi = threadIdx.x >> 6;
    const int r0 = blockIdx.x * 32;
    const int nb = wi * 32;
    const int nn = lane & 15;
    const int kq = (lane >> 4) * 8;

    bf16x8 bh[4][2], bl[4][2];
#pragma unroll
    for (int c = 0; c < 4; c++)
#pragma unroll
        for (int t = 0; t < 2; t++) {
            int off = (nb + t * 16 + nn) * 128 + c * 32 + kq;
            bh[c][t] = *(const bf16x8*)(Wthi + off);
            bl[c][t] = *(const bf16x8*)(Wtlo + off);
        }

    f32x4 acc[2][2] = {};
#pragma unroll
    for (int c = 0; c < 4; c++) {
        bf16x8 ah[2], al[2];
#pragma unroll
        for (int m = 0; m < 2; m++) {
            size_t off = (size_t)(r0 + m * 16 + nn) * 128 + c * 32 + kq;
            ah[m] = *(const bf16x8*)(Ahi + off);
            al[m] = *(const bf16x8*)(Alo + off);
        }
#pragma unroll
        for (int m = 0; m < 2; m++)
#pragma unroll
            for (int t = 0; t < 2; t++) {
                acc[m][t] = __builtin_amdgcn_mfma_f32_16x16x32_bf16(ah[m], bh[c][t], acc[m][t], 0, 0, 0);
                acc[m][t] = __builtin_amdgcn_mfma_f32_16x16x32_bf16(ah[m], bl[c][t], acc[m][t], 0, 0, 0);
                acc[m][t] = __builtin_amdgcn_mfma_f32_16x16x32_bf16(al[m], bh[c][t], acc[m][t], 0, 0, 0);
            }
    }

    const int quad = lane >> 4;
#pragma unroll
    for (int m = 0; m < 2; m++) {
#pragma unroll
        for (int reg = 0; reg < 4; reg++) {
            int r = r0 + m * 16 + quad * 4 + reg;
            float dv = dinv[r];
#pragma unroll
            for (int t = 0; t < 2; t++)
                out[(size_t)r * 128 + nb + t * 16 + nn] = (_Float16)(acc[m][t][reg] * dv);
        }
    }
}

// NC=40 (3 n-tiles, cols 0..47 padded). Each wave owns its own 32-row strip, all 48 cols.
__launch_bounds__(256)
__global__ void k_gemm40(const unsigned short* __restrict__ Ahi, const unsigned short* __restrict__ Alo,
                         const unsigned short* __restrict__ Wthi, const unsigned short* __restrict__ Wtlo,
                         const float* __restrict__ dinv, _Float16* __restrict__ out) {
    const int lane = threadIdx.x & 63;
    const int wi = threadIdx.x >> 6;
    const int r0 = (blockIdx.x * 4 + wi) * 32;
    const int nn = lane & 15;
    const int kq = (lane >> 4) * 8;

    bf16x8 bh[4][3], bl[4][3];
#pragma unroll
    for (int c = 0; c < 4; c++)
#pragma unroll
        for (int t = 0; t < 3; t++) {
            int off = (t * 16 + nn) * 128 + c * 32 + kq;
            bh[c][t] = *(const bf16x8*)(Wthi + off);
            bl[c][t] = *(const bf16x8*)(Wtlo + off);
        }

    f32x4 acc[2][3] = {};
#pragma unroll
    for (int c = 0; c < 4; c++) {
        bf16x8 ah[2], al[2];
#pragma unroll
        for (int m = 0; m < 2; m++) {
            int rr = min(r0 + m * 16 + nn, N_NODES - 1);
            size_t off = (size_t)rr * 128 + c * 32 + kq;
            ah[m] = *(const bf16x8*)(Ahi + off);
            al[m] = *(const bf16x8*)(Alo + off);
        }
#pragma unroll
        for (int m = 0; m < 2; m++)
#pragma unroll
            for (int t = 0; t < 3; t++) {
                acc[m][t] = __builtin_amdgcn_mfma_f32_16x16x32_bf16(ah[m], bh[c][t], acc[m][t], 0, 0, 0);
                acc[m][t] = __builtin_amdgcn_mfma_f32_16x16x32_bf16(ah[m], bl[c][t], acc[m][t], 0, 0, 0);
                acc[m][t] = __builtin_amdgcn_mfma_f32_16x16x32_bf16(al[m], bh[c][t], acc[m][t], 0, 0, 0);
            }
    }

    const int quad = lane >> 4;
#pragma unroll
    for (int m = 0; m < 2; m++) {
#pragma unroll
        for (int reg = 0; reg < 4; reg++) {
            int r = r0 + m * 16 + quad * 4 + reg;
            if (r < N_NODES) {
                float dv = dinv[r];
#pragma unroll
                for (int t = 0; t < 3; t++) {
                    int col = t * 16 + nn;
                    if (col < 40)
                        out[(size_t)r * 40 + col] = (_Float16)(acc[m][t][reg] * dv);
                }
            }
        }
    }
}

// ---------------- Aggregation (F=128): wave per row; gather fp16; write split-bf16 planes ----

__launch_bounds__(256)
__global__ void k_agg128(const _Float16* __restrict__ hp, const int* __restrict__ rowptr,
                         const int* __restrict__ colidx, const float* __restrict__ dinv,
                         const float* __restrict__ bias, unsigned short* __restrict__ ohi,
                         unsigned short* __restrict__ olo) {
    const int r = (blockIdx.x * blockDim.x + threadIdx.x) >> 6;
    const int lane = threadIdx.x & 63;
    if (r >= N_NODES) return;
    const int c0 = lane * 2;

    h2v sv = *(const h2v*)(hp + (size_t)r * 128 + c0);
    float ax = (float)sv.x, ay = (float)sv.y;  // self-loop term
    int e = rowptr[r];
    const int e1 = rowptr[r + 1];
    for (; e + 4 <= e1; e += 4) {
        int s0 = colidx[e], s1 = colidx[e + 1], s2 = colidx[e + 2], s3 = colidx[e + 3];
        h2v v0 = *(const h2v*)(hp + (size_t)s0 * 128 + c0);
        h2v v1 = *(const h2v*)(hp + (size_t)s1 * 128 + c0);
        h2v v2 = *(const h2v*)(hp + (size_t)s2 * 128 + c0);
        h2v v3 = *(const h2v*)(hp + (size_t)s3 * 128 + c0);
        ax += ((float)v0.x + (float)v1.x) + ((float)v2.x + (float)v3.x);
        ay += ((float)v0.y + (float)v1.y) + ((float)v2.y + (float)v3.y);
    }
    for (; e < e1; e++) {
        int s = colidx[e];
        h2v v = *(const h2v*)(hp + (size_t)s * 128 + c0);
        ax += (float)v.x;
        ay += (float)v.y;
    }
    float dv = dinv[r];
    float2 b = ((const float2*)bias)[lane];
    float ox = fmaxf(fmaf(dv, ax, b.x), 0.f);
    float oy = fmaxf(fmaf(dv, ay, b.y), 0.f);
    ushort2 h, l;
    split_bf(ox, h.x, l.x);
    split_bf(oy, h.y, l.y);
    *(ushort2*)(ohi + (size_t)r * 128 + c0) = h;
    *(ushort2*)(olo + (size_t)r * 128 + c0) = l;
}

// ---------------- Final aggregation (F=40, fp16 gather) + fused log_softmax ----------------

__launch_bounds__(256)
__global__ void k_agg_out(const _Float16* __restrict__ hp, const int* __restrict__ rowptr,
                          const int* __restrict__ colidx, const float* __restrict__ dinv,
                          float* __restrict__ out) {
    const int r = (blockIdx.x * blockDim.x + threadIdx.x) >> 6;
    const int lane = threadIdx.x & 63;
    if (r >= N_NODES) return;
    const bool act = lane < 40;

    float acc = act ? (float)hp[(size_t)r * 40 + lane] : 0.f;  // self-loop
    int e = rowptr[r];
    const int e1 = rowptr[r + 1];
    for (; e + 4 <= e1; e += 4) {
        int s0 = colidx[e], s1 = colidx[e + 1], s2 = colidx[e + 2], s3 = colidx[e + 3];
        if (act) {
            float v0 = (float)hp[(size_t)s0 * 40 + lane];
            float v1 = (float)hp[(size_t)s1 * 40 + lane];
            float v2 = (float)hp[(size_t)s2 * 40 + lane];
            float v3 = (float)hp[(size_t)s3 * 40 + lane];
            acc += (v0 + v1) + (v2 + v3);
        }
    }
    for (; e < e1; e++) {
        int s = colidx[e];
        if (act) acc += (float)hp[(size_t)s * 40 + lane];
    }
    float z = act ? dinv[r] * acc : -INFINITY;
    float m = z;
    for (int off = 32; off; off >>= 1) m = fmaxf(m, __shfl_xor(m, off));
    float ex = act ? __expf(z - m) : 0.f;
    float se = ex;
    for (int off = 32; off; off >>= 1) se += __shfl_xor(se, off);
    if (act) out[(size_t)r * 40 + lane] = z - m - __logf(se);
}

// ---------------- launch ----------------

extern "C" void kernel_launch(void* const* d_in, const int* in_sizes, int n_in,
                              void* d_out, int out_size, void* d_ws, size_t ws_size,
                              hipStream_t stream) {
    const float* x     = (const float*)d_in[0];
    const int*   ei    = (const int*)d_in[1];
    const float* W_in  = (const float*)d_in[2];
    const float* b_in  = (const float*)d_in[3];
    const float* W_mid = (const float*)d_in[4];
    const float* b_mid = (const float*)d_in[5];
    const float* W_out = (const float*)d_in[6];
    float* out = (float*)d_out;

    const int* srcv = ei;
    const int* dstv = ei + N_EDGES;

    char* w = (char*)d_ws;
    float* dinv  = (float*)(w);                    // 400 KB
    int* rowptr  = (int*)(w + (1ull << 20));
    int* cursor  = (int*)(w + (2ull << 20));
    int* bsums   = (int*)(w + (3ull << 20));
    int* colidx  = (int*)(w + (4ull << 20));       // 6.4 MB -> ends ~10.4 MB
    unsigned short* Wt1h = (unsigned short*)(w + (11ull << 20));
    unsigned short* Wt1l = Wt1h + 128 * 128;
    unsigned short* Wt2h = Wt1l + 128 * 128;
    unsigned short* Wt2l = Wt2h + 128 * 128;
    unsigned short* Wt3h = Wt2l + 128 * 128;
    unsigned short* Wt3l = Wt3h + 48 * 128;
    _Float16* hprime = (_Float16*)(w + (12ull << 20));        // 25.6 MB -> ends 37.6
    unsigned short* Phi = (unsigned short*)(w + (40ull << 20)); // 25.6 MB
    unsigned short* Plo = (unsigned short*)(w + (68ull << 20)); // 25.6 MB -> ends 93.6

    const int NB_N = (N_NODES + 255) / 256;
    const int NB_E = (N_EDGES + 255) / 256;
    const int NB_SCAN = (N_NODES + 1023) / 1024;

    // CSR + dinv
    k_zero_int<<<NB_N, 256, 0, stream>>>(cursor, N_NODES);
    k_count<<<NB_E, 256, 0, stream>>>(dstv, cursor);
    k_dinv<<<NB_N, 256, 0, stream>>>(cursor, dinv);
    k_scan1<<<NB_SCAN, 1024, 0, stream>>>(cursor, rowptr, bsums);
    k_scan2<<<1, 128, 0, stream>>>(bsums, NB_SCAN);
    k_scan3<<<NB_SCAN, 1024, 0, stream>>>(rowptr, bsums, cursor);
    k_fill<<<NB_E, 256, 0, stream>>>(srcv, dstv, rowptr, cursor, colidx);

    // input/weight prep
    k_split_x<<<(N_NODES * 128 / 4 + 255) / 256, 256, 0, stream>>>(x, Phi, Plo);
    k_wprep<<<(128 * 128 + 255) / 256, 256, 0, stream>>>(W_in, 128, 128, Wt1h, Wt1l);
    k_wprep<<<(128 * 128 + 255) / 256, 256, 0, stream>>>(W_mid, 128, 128, Wt2h, Wt2l);
    k_wprep<<<(48 * 128 + 255) / 256, 256, 0, stream>>>(W_out, 40, 48, Wt3h, Wt3l);

    const int AGG_BLOCKS = N_NODES / 4;
    const int GEMM_BLOCKS = N_NODES / 32;  // 3125

    // Layer 1
    k_gemm128<<<GEMM_BLOCKS, 256, 0, stream>>>(Phi, Plo, Wt1h, Wt1l, dinv, hprime);
    k_agg128<<<AGG_BLOCKS, 256, 0, stream>>>(hprime, rowptr, colidx, dinv, b_in, Phi, Plo);
    // Layer 2
    k_gemm128<<<GEMM_BLOCKS, 256, 0, stream>>>(Phi, Plo, Wt2h, Wt2l, dinv, hprime);
    k_agg128<<<AGG_BLOCKS, 256, 0, stream>>>(hprime, rowptr, colidx, dinv, b_mid, Phi, Plo);
    // Layer 3 + log_softmax
    k_gemm40<<<(N_NODES + 127) / 128, 256, 0, stream>>>(Phi, Plo, Wt3h, Wt3l, dinv, hprime);
    k_agg_out<<<AGG_BLOCKS, 256, 0, stream>>>(hprime, rowptr, colidx, dinv, out);
}

// Round 3
// 497.370 us; speedup vs baseline: 1.7673x; 1.2453x over previous
//
#include <hip/hip_runtime.h>
#include <math.h>

#define N_NODES 100000
#define N_EDGES 1600000
#define NBUCK 391          // ceil(100000 / 256)

typedef __attribute__((ext_vector_type(8))) _Float16 h8v;
typedef __attribute__((ext_vector_type(4))) float f32x4;
typedef __attribute__((ext_vector_type(2))) _Float16 h2v;

// ---------------- CSR build (bucketed) ----------------

__global__ void k_zero_int(int* __restrict__ p, int n) {
    int i = blockIdx.x * blockDim.x + threadIdx.x;
    if (i < n) p[i] = 0;
}

// Pass A: global bucket histogram via per-block LDS histograms.
__launch_bounds__(256)
__global__ void k_bhist(const int* __restrict__ dstv, int* __restrict__ bcnt) {
    __shared__ int hist[NBUCK];
    const int tid = threadIdx.x;
    for (int t = tid; t < NBUCK; t += 256) hist[t] = 0;
    __syncthreads();
    const int base = blockIdx.x * 4096;
#pragma unroll
    for (int i = 0; i < 16; i++) {
        int e = base + i * 256 + tid;
        if (e < N_EDGES) atomicAdd(&hist[dstv[e] >> 8], 1);
    }
    __syncthreads();
    for (int t = tid; t < NBUCK; t += 256)
        if (hist[t]) atomicAdd(&bcnt[t], hist[t]);
}

// Pass B: scan bucket counts -> bucket_ptr (exclusive) + init bucket_cursor.
__global__ void k_bscan(const int* __restrict__ bcnt, int* __restrict__ bptr,
                        int* __restrict__ bcur) {
    __shared__ int s[512];
    int tid = threadIdx.x;
    int v = (tid < NBUCK) ? bcnt[tid] : 0;
    int x = v;
    s[tid] = x;
    __syncthreads();
    for (int d = 1; d < 512; d <<= 1) {
        int t = (tid >= d) ? s[tid - d] : 0;
        __syncthreads();
        x += t;
        s[tid] = x;
        __syncthreads();
    }
    if (tid < NBUCK) {
        bptr[tid] = x - v;
        bcur[tid] = x - v;
    }
    if (tid == NBUCK - 1) bptr[NBUCK] = x;
}

// Pass C: partition (src,dst) into bucket-ordered ebuf.
__launch_bounds__(256)
__global__ void k_bpart(const int* __restrict__ srcv, const int* __restrict__ dstv,
                        int* __restrict__ bcur, int2* __restrict__ ebuf) {
    __shared__ int hist[NBUCK];
    __shared__ int cur[NBUCK];
    const int tid = threadIdx.x;
    for (int t = tid; t < NBUCK; t += 256) hist[t] = 0;
    __syncthreads();
    const int base = blockIdx.x * 4096;
#pragma unroll
    for (int i = 0; i < 16; i++) {
        int e = base + i * 256 + tid;
        if (e < N_EDGES) atomicAdd(&hist[dstv[e] >> 8], 1);
    }
    __syncthreads();
    for (int t = tid; t < NBUCK; t += 256)
        cur[t] = hist[t] ? atomicAdd(&bcur[t], hist[t]) : 0;
    __syncthreads();
#pragma unroll
    for (int i = 0; i < 16; i++) {
        int e = base + i * 256 + tid;
        if (e < N_EDGES) {
            int d = dstv[e];
            int p = atomicAdd(&cur[d >> 8], 1);
            ebuf[p] = make_int2(srcv[e], d);
        }
    }
}

// Pass C2: per-bucket degree histogram (LDS), coalesced degree writes.
__launch_bounds__(256)
__global__ void k_bdeg(const int2* __restrict__ ebuf, const int* __restrict__ bptr,
                       int* __restrict__ deg) {
    __shared__ int d[256];
    const int tid = threadIdx.x;
    d[tid] = 0;
    __syncthreads();
    const int b = blockIdx.x;
    const int e0 = bptr[b], e1 = bptr[b + 1];
    for (int e = e0 + tid; e < e1; e += 256) atomicAdd(&d[ebuf[e].y & 255], 1);
    __syncthreads();
    int node = b * 256 + tid;
    if (node < N_NODES) deg[node] = d[tid];
}

// Pass D: fill colidx using LDS cursors (per-bucket node window).
__launch_bounds__(256)
__global__ void k_bfill(const int2* __restrict__ ebuf, const int* __restrict__ bptr,
                        const int* __restrict__ rowptr, int* __restrict__ colidx) {
    __shared__ int cur[256];
    const int tid = threadIdx.x;
    cur[tid] = 0;
    __syncthreads();
    const int b = blockIdx.x;
    const int e0 = bptr[b], e1 = bptr[b + 1];
    for (int e = e0 + tid; e < e1; e += 256) {
        int2 sd = ebuf[e];
        int lpos = atomicAdd(&cur[sd.y & 255], 1);
        colidx[rowptr[sd.y] + lpos] = sd.x;
    }
}

__global__ void k_dinv(const int* __restrict__ deg, float* __restrict__ dinv) {
    int i = blockIdx.x * blockDim.x + threadIdx.x;
    if (i < N_NODES) dinv[i] = rsqrtf((float)(deg[i] + 1));  // +1 self-loop
}

// ---------------- node-degree scan -> rowptr ----------------

__global__ void k_scan1(const int* __restrict__ cnt, int* __restrict__ rowptr,
                        int* __restrict__ bsums) {
    __shared__ int s[1024];
    int tid = threadIdx.x;
    int i = blockIdx.x * 1024 + tid;
    int v = (i < N_NODES) ? cnt[i] : 0;
    int x = v;
    s[tid] = x;
    __syncthreads();
    for (int d = 1; d < 1024; d <<= 1) {
        int t = (tid >= d) ? s[tid - d] : 0;
        __syncthreads();
        x += t;
        s[tid] = x;
        __syncthreads();
    }
    if (i < N_NODES) rowptr[i] = x - v;
    if (tid == 1023) bsums[blockIdx.x] = x;
}

__global__ void k_scan2(int* __restrict__ bsums, int nb) {
    __shared__ int s[128];
    int tid = threadIdx.x;
    int v = (tid < nb) ? bsums[tid] : 0;
    int x = v;
    s[tid] = x;
    __syncthreads();
    for (int d = 1; d < 128; d <<= 1) {
        int t = (tid >= d) ? s[tid - d] : 0;
        __syncthreads();
        x += t;
        s[tid] = x;
        __syncthreads();
    }
    if (tid < nb) bsums[tid] = x - v;
}

__global__ void k_scan3(int* __restrict__ rowptr, const int* __restrict__ bsums) {
    int i = blockIdx.x * 1024 + threadIdx.x;
    if (i < N_NODES) rowptr[i] += bsums[blockIdx.x];
    if (i == 0) rowptr[N_NODES] = N_EDGES;
}

// ---------------- input / weight conversion ----------------

__global__ void k_cvt_x(const float* __restrict__ x, _Float16* __restrict__ xh) {
    int i = blockIdx.x * blockDim.x + threadIdx.x;
    int base = i * 4;
    if (base >= N_NODES * 128) return;
    float4 v = *(const float4*)(x + base);
    h2v a = {(_Float16)v.x, (_Float16)v.y};
    h2v b = {(_Float16)v.z, (_Float16)v.w};
    *(h2v*)(xh + base) = a;
    *(h2v*)(xh + base + 2) = b;
}

// W [128 x ncols] fp32 -> Wt hi/lo [ntcols x 128] f16 (transposed, zero-padded cols)
__global__ void k_wprep(const float* __restrict__ W, int ncols, int ntcols,
                        _Float16* __restrict__ Wthi, _Float16* __restrict__ Wtlo) {
    int idx = blockIdx.x * blockDim.x + threadIdx.x;
    if (idx >= ntcols * 128) return;
    int n = idx / 128, k = idx % 128;
    float v = (n < ncols) ? W[k * ncols + n] : 0.f;
    _Float16 hi = (_Float16)v;
    _Float16 lo = (_Float16)(v - (float)hi);
    Wthi[n * 128 + k] = hi;
    Wtlo[n * 128 + k] = lo;
}

// ---------------- MFMA GEMM (f16): h'[r,c] = dinv[r] * sum_k A[r,k] W[k,c] ----------------
// W = Whi + Wlo (split f16): 2 MFMAs per tile. A single fp16 plane.
// Block: 4 waves, 32 rows; wave wi covers cols [wi*32, wi*32+32).

__launch_bounds__(256)
__global__ void k_gemm128(const _Float16* __restrict__ A,
                          const _Float16* __restrict__ Wthi, const _Float16* __restrict__ Wtlo,
                          const float* __restrict__ dinv, _Float16* __restrict__ out) {
    const int lane = threadIdx.x & 63;
    const int wi = threadIdx.x >> 6;
    const int r0 = blockIdx.x * 32;
    const int nb = wi * 32;
    const int nn = lane & 15;
    const int kq = (lane >> 4) * 8;

    h8v bh[4][2], bl[4][2];
#pragma unroll
    for (int c = 0; c < 4; c++)
#pragma unroll
        for (int t = 0; t < 2; t++) {
            int off = (nb + t * 16 + nn) * 128 + c * 32 + kq;
            bh[c][t] = *(const h8v*)(Wthi + off);
            bl[c][t] = *(const h8v*)(Wtlo + off);
        }

    f32x4 acc[2][2] = {};
#pragma unroll
    for (int c = 0; c < 4; c++) {
        h8v a[2];
#pragma unroll
        for (int m = 0; m < 2; m++)
            a[m] = *(const h8v*)(A + (size_t)(r0 + m * 16 + nn) * 128 + c * 32 + kq);
#pragma unroll
        for (int m = 0; m < 2; m++)
#pragma unroll
            for (int t = 0; t < 2; t++) {
                acc[m][t] = __builtin_amdgcn_mfma_f32_16x16x32_f16(a[m], bh[c][t], acc[m][t], 0, 0, 0);
                acc[m][t] = __builtin_amdgcn_mfma_f32_16x16x32_f16(a[m], bl[c][t], acc[m][t], 0, 0, 0);
            }
    }

    const int quad = lane >> 4;
#pragma unroll
    for (int m = 0; m < 2; m++) {
#pragma unroll
        for (int reg = 0; reg < 4; reg++) {
            int r = r0 + m * 16 + quad * 4 + reg;
            float dv = dinv[r];
#pragma unroll
            for (int t = 0; t < 2; t++)
                out[(size_t)r * 128 + nb + t * 16 + nn] = (_Float16)(acc[m][t][reg] * dv);
        }
    }
}

// NC=40 (3 n-tiles, cols padded to 48). Wave owns its own 32-row strip, all cols.
__launch_bounds__(256)
__global__ void k_gemm40(const _Float16* __restrict__ A,
                         const _Float16* __restrict__ Wthi, const _Float16* __restrict__ Wtlo,
                         const float* __restrict__ dinv, _Float16* __restrict__ out) {
    const int lane = threadIdx.x & 63;
    const int wi = threadIdx.x >> 6;
    const int r0 = (blockIdx.x * 4 + wi) * 32;
    const int nn = lane & 15;
    const int kq = (lane >> 4) * 8;

    h8v bh[4][3], bl[4][3];
#pragma unroll
    for (int c = 0; c < 4; c++)
#pragma unroll
        for (int t = 0; t < 3; t++) {
            int off = (t * 16 + nn) * 128 + c * 32 + kq;
            bh[c][t] = *(const h8v*)(Wthi + off);
            bl[c][t] = *(const h8v*)(Wtlo + off);
        }

    f32x4 acc[2][3] = {};
#pragma unroll
    for (int c = 0; c < 4; c++) {
        h8v a[2];
#pragma unroll
        for (int m = 0; m < 2; m++) {
            int rr = min(r0 + m * 16 + nn, N_NODES - 1);
            a[m] = *(const h8v*)(A + (size_t)rr * 128 + c * 32 + kq);
        }
#pragma unroll
        for (int m = 0; m < 2; m++)
#pragma unroll
            for (int t = 0; t < 3; t++) {
                acc[m][t] = __builtin_amdgcn_mfma_f32_16x16x32_f16(a[m], bh[c][t], acc[m][t], 0, 0, 0);
                acc[m][t] = __builtin_amdgcn_mfma_f32_16x16x32_f16(a[m], bl[c][t], acc[m][t], 0, 0, 0);
            }
    }

    const int quad = lane >> 4;
#pragma unroll
    for (int m = 0; m < 2; m++) {
#pragma unroll
        for (int reg = 0; reg < 4; reg++) {
            int r = r0 + m * 16 + quad * 4 + reg;
            if (r < N_NODES) {
                float dv = dinv[r];
#pragma unroll
                for (int t = 0; t < 3; t++) {
                    int col = t * 16 + nn;
                    if (col < 40)
                        out[(size_t)r * 40 + col] = (_Float16)(acc[m][t][reg] * dv);
                }
            }
        }
    }
}

// ---------------- Aggregation (F=128): wave per row; fp16 gather; fp16 out ----------------

__launch_bounds__(256)
__global__ void k_agg128(const _Float16* __restrict__ hp, const int* __restrict__ rowptr,
                         const int* __restrict__ colidx, const float* __restrict__ dinv,
                         const float* __restrict__ bias, _Float16* __restrict__ outp) {
    const int r = (blockIdx.x * blockDim.x + threadIdx.x) >> 6;
    const int lane = threadIdx.x & 63;
    if (r >= N_NODES) return;
    const int c0 = lane * 2;

    h2v sv = *(const h2v*)(hp + (size_t)r * 128 + c0);
    float ax = (float)sv.x, ay = (float)sv.y;  // self-loop term
    int e = rowptr[r];
    const int e1 = rowptr[r + 1];
    for (; e + 4 <= e1; e += 4) {
        int s0 = colidx[e], s1 = colidx[e + 1], s2 = colidx[e + 2], s3 = colidx[e + 3];
        h2v v0 = *(const h2v*)(hp + (size_t)s0 * 128 + c0);
        h2v v1 = *(const h2v*)(hp + (size_t)s1 * 128 + c0);
        h2v v2 = *(const h2v*)(hp + (size_t)s2 * 128 + c0);
        h2v v3 = *(const h2v*)(hp + (size_t)s3 * 128 + c0);
        ax += ((float)v0.x + (float)v1.x) + ((float)v2.x + (float)v3.x);
        ay += ((float)v0.y + (float)v1.y) + ((float)v2.y + (float)v3.y);
    }
    for (; e < e1; e++) {
        int s = colidx[e];
        h2v v = *(const h2v*)(hp + (size_t)s * 128 + c0);
        ax += (float)v.x;
        ay += (float)v.y;
    }
    float dv = dinv[r];
    float2 b = ((const float2*)bias)[lane];
    float ox = fmaxf(fmaf(dv, ax, b.x), 0.f);
    float oy = fmaxf(fmaf(dv, ay, b.y), 0.f);
    h2v o = {(_Float16)ox, (_Float16)oy};
    *(h2v*)(outp + (size_t)r * 128 + c0) = o;
}

// ---------------- Final aggregation (F=40) + fused log_softmax ----------------

__launch_bounds__(256)
__global__ void k_agg_out(const _Float16* __restrict__ hp, const int* __restrict__ rowptr,
                          const int* __restrict__ colidx, const float* __restrict__ dinv,
                          float* __restrict__ out) {
    const int r = (blockIdx.x * blockDim.x + threadIdx.x) >> 6;
    const int lane = threadIdx.x & 63;
    if (r >= N_NODES) return;
    const bool act = lane < 40;

    float acc = act ? (float)hp[(size_t)r * 40 + lane] : 0.f;  // self-loop
    int e = rowptr[r];
    const int e1 = rowptr[r + 1];
    for (; e + 4 <= e1; e += 4) {
        int s0 = colidx[e], s1 = colidx[e + 1], s2 = colidx[e + 2], s3 = colidx[e + 3];
        if (act) {
            float v0 = (float)hp[(size_t)s0 * 40 + lane];
            float v1 = (float)hp[(size_t)s1 * 40 + lane];
            float v2 = (float)hp[(size_t)s2 * 40 + lane];
            float v3 = (float)hp[(size_t)s3 * 40 + lane];
            acc += (v0 + v1) + (v2 + v3);
        }
    }
    for (; e < e1; e++) {
        int s = colidx[e];
        if (act) acc += (float)hp[(size_t)s * 40 + lane];
    }
    float z = act ? dinv[r] * acc : -INFINITY;
    float m = z;
    for (int off = 32; off; off >>= 1) m = fmaxf(m, __shfl_xor(m, off));
    float ex = act ? __expf(z - m) : 0.f;
    float se = ex;
    for (int off = 32; off; off >>= 1) se += __shfl_xor(se, off);
    if (act) out[(size_t)r * 40 + lane] = z - m - __logf(se);
}

// ---------------- launch ----------------

extern "C" void kernel_launch(void* const* d_in, const int* in_sizes, int n_in,
                              void* d_out, int out_size, void* d_ws, size_t ws_size,
                              hipStream_t stream) {
    const float* x     = (const float*)d_in[0];
    const int*   ei    = (const int*)d_in[1];
    const float* W_in  = (const float*)d_in[2];
    const float* b_in  = (const float*)d_in[3];
    const float* W_mid = (const float*)d_in[4];
    const float* b_mid = (const float*)d_in[5];
    const float* W_out = (const float*)d_in[6];
    float* out = (float*)d_out;

    const int* srcv = ei;
    const int* dstv = ei + N_EDGES;

    char* w = (char*)d_ws;
    float* dinv   = (float*)(w);                       // 400 KB
    int* degarr   = (int*)(w + (1ull << 19));          // 400 KB
    int* rowptr   = (int*)(w + (1ull << 20));          // 400 KB
    int* bsums    = (int*)(w + 1572864);               // small
    int* bcnt     = (int*)(w + 1572864 + 4096);
    int* bptr     = (int*)(w + 1572864 + 8192);
    int* bcur     = (int*)(w + 1572864 + 12288);
    int* colidx   = (int*)(w + (2ull << 20));          // 6.4 MB -> ends 8.4 MB
    int2* ebuf    = (int2*)(w + (9ull << 20));         // 12.8 MB -> ends 21.8 MB
    _Float16* Wt1h = (_Float16*)(w + (22ull << 20));
    _Float16* Wt1l = Wt1h + 128 * 128;
    _Float16* Wt2h = Wt1l + 128 * 128;
    _Float16* Wt2l = Wt2h + 128 * 128;
    _Float16* Wt3h = Wt2l + 128 * 128;
    _Float16* Wt3l = Wt3h + 48 * 128;
    _Float16* buf0 = (_Float16*)(w + (24ull << 20));   // 25.6 MB
    _Float16* buf1 = (_Float16*)(w + (52ull << 20));   // 25.6 MB
    _Float16* buf2 = (_Float16*)(w + (80ull << 20));   // 25.6 MB -> ends ~105.6 MB

    const int NB_N = (N_NODES + 255) / 256;
    const int NB_SCAN = (N_NODES + 1023) / 1024;
    const int NB_PART = (N_EDGES + 4095) / 4096;  // 391

    // CSR build (bucketed)
    k_zero_int<<<2, 256, 0, stream>>>(bcnt, 512);
    k_bhist<<<NB_PART, 256, 0, stream>>>(dstv, bcnt);
    k_bscan<<<1, 512, 0, stream>>>(bcnt, bptr, bcur);
    k_bpart<<<NB_PART, 256, 0, stream>>>(srcv, dstv, bcur, ebuf);
    k_bdeg<<<NBUCK, 256, 0, stream>>>(ebuf, bptr, degarr);
    k_dinv<<<NB_N, 256, 0, stream>>>(degarr, dinv);
    k_scan1<<<NB_SCAN, 1024, 0, stream>>>(degarr, rowptr, bsums);
    k_scan2<<<1, 128, 0, stream>>>(bsums, NB_SCAN);
    k_scan3<<<NB_SCAN, 1024, 0, stream>>>(rowptr, bsums);
    k_bfill<<<NBUCK, 256, 0, stream>>>(ebuf, bptr, rowptr, colidx);

    // input/weight prep
    k_cvt_x<<<(N_NODES * 128 / 4 + 255) / 256, 256, 0, stream>>>(x, buf0);
    k_wprep<<<(128 * 128 + 255) / 256, 256, 0, stream>>>(W_in, 128, 128, Wt1h, Wt1l);
    k_wprep<<<(128 * 128 + 255) / 256, 256, 0, stream>>>(W_mid, 128, 128, Wt2h, Wt2l);
    k_wprep<<<(48 * 128 + 255) / 256, 256, 0, stream>>>(W_out, 40, 48, Wt3h, Wt3l);

    const int AGG_BLOCKS = N_NODES / 4;
    const int GEMM_BLOCKS = N_NODES / 32;

    // Layer 1
    k_gemm128<<<GEMM_BLOCKS, 256, 0, stream>>>(buf0, Wt1h, Wt1l, dinv, buf1);
    k_agg128<<<AGG_BLOCKS, 256, 0, stream>>>(buf1, rowptr, colidx, dinv, b_in, buf2);
    // Layer 2
    k_gemm128<<<GEMM_BLOCKS, 256, 0, stream>>>(buf2, Wt2h, Wt2l, dinv, buf1);
    k_agg128<<<AGG_BLOCKS, 256, 0, stream>>>(buf1, rowptr, colidx, dinv, b_mid, buf0);
    // Layer 3 + log_softmax
    k_gemm40<<<(N_NODES + 127) / 128, 256, 0, stream>>>(buf0, Wt3h, Wt3l, dinv, buf1);
    k_agg_out<<<AGG_BLOCKS, 256, 0, stream>>>(buf1, rowptr, colidx, dinv, out);
}

// Round 4
// 495.019 us; speedup vs baseline: 1.7757x; 1.0048x over previous
//
#include <hip/hip_runtime.h>
#include <math.h>

#define N_NODES 100000
#define N_EDGES 1600000
#define NBUCK 391          // ceil(100000 / 256)

typedef __attribute__((ext_vector_type(8))) _Float16 h8v;
typedef __attribute__((ext_vector_type(4))) float f32x4;
typedef __attribute__((ext_vector_type(2))) _Float16 h2v;

// ---------------- CSR build (bucketed, packed) ----------------

__global__ void k_zero_int(int* __restrict__ p, int n) {
    int i = blockIdx.x * blockDim.x + threadIdx.x;
    if (i < n) p[i] = 0;
}

// Pass A: global bucket histogram via per-block LDS histograms.
__launch_bounds__(256)
__global__ void k_bhist(const int* __restrict__ dstv, int* __restrict__ bcnt) {
    __shared__ int hist[NBUCK];
    const int tid = threadIdx.x;
    for (int t = tid; t < NBUCK; t += 256) hist[t] = 0;
    __syncthreads();
    const int base = blockIdx.x * 4096;
#pragma unroll
    for (int i = 0; i < 16; i++) {
        int e = base + i * 256 + tid;
        if (e < N_EDGES) atomicAdd(&hist[dstv[e] >> 8], 1);
    }
    __syncthreads();
    for (int t = tid; t < NBUCK; t += 256)
        if (hist[t]) atomicAdd(&bcnt[t], hist[t]);
}

// Pass B: scan bucket counts -> bptr (exclusive) + init bucket cursors.
__global__ void k_bscan(const int* __restrict__ bcnt, int* __restrict__ bptr,
                        int* __restrict__ bcur) {
    __shared__ int s[512];
    int tid = threadIdx.x;
    int v = (tid < NBUCK) ? bcnt[tid] : 0;
    int x = v;
    s[tid] = x;
    __syncthreads();
    for (int d = 1; d < 512; d <<= 1) {
        int t = (tid >= d) ? s[tid - d] : 0;
        __syncthreads();
        x += t;
        s[tid] = x;
        __syncthreads();
    }
    if (tid < NBUCK) {
        bptr[tid] = x - v;
        bcur[tid] = x - v;
    }
    if (tid == NBUCK - 1) bptr[NBUCK] = x;
}

// Pass C: partition packed (src<<8 | dst&255) into bucket-ordered ebuf.
__launch_bounds__(256)
__global__ void k_bpart(const int* __restrict__ srcv, const int* __restrict__ dstv,
                        int* __restrict__ bcur, unsigned int* __restrict__ ebuf) {
    __shared__ int hist[NBUCK];
    __shared__ int cur[NBUCK];
    const int tid = threadIdx.x;
    for (int t = tid; t < NBUCK; t += 256) hist[t] = 0;
    __syncthreads();
    const int base = blockIdx.x * 4096;
#pragma unroll
    for (int i = 0; i < 16; i++) {
        int e = base + i * 256 + tid;
        if (e < N_EDGES) atomicAdd(&hist[dstv[e] >> 8], 1);
    }
    __syncthreads();
    for (int t = tid; t < NBUCK; t += 256)
        cur[t] = hist[t] ? atomicAdd(&bcur[t], hist[t]) : 0;
    __syncthreads();
#pragma unroll
    for (int i = 0; i < 16; i++) {
        int e = base + i * 256 + tid;
        if (e < N_EDGES) {
            int d = dstv[e];
            int p = atomicAdd(&cur[d >> 8], 1);
            ebuf[p] = ((unsigned int)srcv[e] << 8) | (unsigned int)(d & 255);
        }
    }
}

// Pass D: per-bucket degree histogram + in-block scan -> rowptr + dinv (fused).
__launch_bounds__(256)
__global__ void k_brow(const unsigned int* __restrict__ ebuf, const int* __restrict__ bptr,
                       int* __restrict__ rowptr, float* __restrict__ dinv) {
    __shared__ int cnt[256];
    __shared__ int s[256];
    const int tid = threadIdx.x;
    cnt[tid] = 0;
    __syncthreads();
    const int b = blockIdx.x;
    const int e0 = bptr[b], e1 = bptr[b + 1];
    for (int e = e0 + tid; e < e1; e += 256) atomicAdd(&cnt[ebuf[e] & 255u], 1);
    __syncthreads();
    int v = cnt[tid];
    int x = v;
    s[tid] = x;
    __syncthreads();
    for (int d = 1; d < 256; d <<= 1) {
        int t = (tid >= d) ? s[tid - d] : 0;
        __syncthreads();
        x += t;
        s[tid] = x;
        __syncthreads();
    }
    int node = b * 256 + tid;
    if (node < N_NODES) {
        rowptr[node] = e0 + x - v;
        dinv[node] = rsqrtf((float)(v + 1));  // +1 self-loop
        if (node == N_NODES - 1) rowptr[N_NODES] = N_EDGES;
    }
}

// Pass E: fill colidx; LDS cursors seeded from rowptr.
__launch_bounds__(256)
__global__ void k_bfill(const unsigned int* __restrict__ ebuf, const int* __restrict__ bptr,
                        const int* __restrict__ rowptr, int* __restrict__ colidx) {
    __shared__ int cur[256];
    const int tid = threadIdx.x;
    const int b = blockIdx.x;
    int node = b * 256 + tid;
    cur[tid] = (node < N_NODES) ? rowptr[node] : 0;
    __syncthreads();
    const int e0 = bptr[b], e1 = bptr[b + 1];
    for (int e = e0 + tid; e < e1; e += 256) {
        unsigned int sd = ebuf[e];
        int pos = atomicAdd(&cur[sd & 255u], 1);
        colidx[pos] = (int)(sd >> 8);
    }
}

// ---------------- weight conversion ----------------

// W [128 x ncols] fp32 -> Wt hi/lo [ntcols x 128] f16 (transposed, zero-padded cols)
__global__ void k_wprep(const float* __restrict__ W, int ncols, int ntcols,
                        _Float16* __restrict__ Wthi, _Float16* __restrict__ Wtlo) {
    int idx = blockIdx.x * blockDim.x + threadIdx.x;
    if (idx >= ntcols * 128) return;
    int n = idx / 128, k = idx % 128;
    float v = (n < ncols) ? W[k * ncols + n] : 0.f;
    _Float16 hi = (_Float16)v;
    _Float16 lo = (_Float16)(v - (float)hi);
    Wthi[n * 128 + k] = hi;
    Wtlo[n * 128 + k] = lo;
}

// ---------------- MFMA GEMMs ----------------
// W = Whi + Wlo (split f16): 2 MFMAs per tile. Block: 4 waves, 32 rows;
// wave wi covers cols [wi*32, wi*32+32).

// Layer-1 variant: A is fp32 (raw x), converted in-register.
__launch_bounds__(256)
__global__ void k_gemm128_f32(const float* __restrict__ Af,
                              const _Float16* __restrict__ Wthi, const _Float16* __restrict__ Wtlo,
                              const float* __restrict__ dinv, _Float16* __restrict__ out) {
    const int lane = threadIdx.x & 63;
    const int wi = threadIdx.x >> 6;
    const int r0 = blockIdx.x * 32;
    const int nb = wi * 32;
    const int nn = lane & 15;
    const int kq = (lane >> 4) * 8;

    h8v bh[4][2], bl[4][2];
#pragma unroll
    for (int c = 0; c < 4; c++)
#pragma unroll
        for (int t = 0; t < 2; t++) {
            int off = (nb + t * 16 + nn) * 128 + c * 32 + kq;
            bh[c][t] = *(const h8v*)(Wthi + off);
            bl[c][t] = *(const h8v*)(Wtlo + off);
        }

    f32x4 acc[2][2] = {};
#pragma unroll
    for (int c = 0; c < 4; c++) {
        h8v a[2];
#pragma unroll
        for (int m = 0; m < 2; m++) {
            const float* p = Af + (size_t)(r0 + m * 16 + nn) * 128 + c * 32 + kq;
            float4 p0 = *(const float4*)p;
            float4 p1 = *(const float4*)(p + 4);
            h8v av = {(_Float16)p0.x, (_Float16)p0.y, (_Float16)p0.z, (_Float16)p0.w,
                      (_Float16)p1.x, (_Float16)p1.y, (_Float16)p1.z, (_Float16)p1.w};
            a[m] = av;
        }
#pragma unroll
        for (int m = 0; m < 2; m++)
#pragma unroll
            for (int t = 0; t < 2; t++) {
                acc[m][t] = __builtin_amdgcn_mfma_f32_16x16x32_f16(a[m], bh[c][t], acc[m][t], 0, 0, 0);
                acc[m][t] = __builtin_amdgcn_mfma_f32_16x16x32_f16(a[m], bl[c][t], acc[m][t], 0, 0, 0);
            }
    }

    const int quad = lane >> 4;
#pragma unroll
    for (int m = 0; m < 2; m++) {
#pragma unroll
        for (int reg = 0; reg < 4; reg++) {
            int r = r0 + m * 16 + quad * 4 + reg;
            float dv = dinv[r];
#pragma unroll
            for (int t = 0; t < 2; t++)
                out[(size_t)r * 128 + nb + t * 16 + nn] = (_Float16)(acc[m][t][reg] * dv);
        }
    }
}

__launch_bounds__(256)
__global__ void k_gemm128(const _Float16* __restrict__ A,
                          const _Float16* __restrict__ Wthi, const _Float16* __restrict__ Wtlo,
                          const float* __restrict__ dinv, _Float16* __restrict__ out) {
    const int lane = threadIdx.x & 63;
    const int wi = threadIdx.x >> 6;
    const int r0 = blockIdx.x * 32;
    const int nb = wi * 32;
    const int nn = lane & 15;
    const int kq = (lane >> 4) * 8;

    h8v bh[4][2], bl[4][2];
#pragma unroll
    for (int c = 0; c < 4; c++)
#pragma unroll
        for (int t = 0; t < 2; t++) {
            int off = (nb + t * 16 + nn) * 128 + c * 32 + kq;
            bh[c][t] = *(const h8v*)(Wthi + off);
            bl[c][t] = *(const h8v*)(Wtlo + off);
        }

    f32x4 acc[2][2] = {};
#pragma unroll
    for (int c = 0; c < 4; c++) {
        h8v a[2];
#pragma unroll
        for (int m = 0; m < 2; m++)
            a[m] = *(const h8v*)(A + (size_t)(r0 + m * 16 + nn) * 128 + c * 32 + kq);
#pragma unroll
        for (int m = 0; m < 2; m++)
#pragma unroll
            for (int t = 0; t < 2; t++) {
                acc[m][t] = __builtin_amdgcn_mfma_f32_16x16x32_f16(a[m], bh[c][t], acc[m][t], 0, 0, 0);
                acc[m][t] = __builtin_amdgcn_mfma_f32_16x16x32_f16(a[m], bl[c][t], acc[m][t], 0, 0, 0);
            }
    }

    const int quad = lane >> 4;
#pragma unroll
    for (int m = 0; m < 2; m++) {
#pragma unroll
        for (int reg = 0; reg < 4; reg++) {
            int r = r0 + m * 16 + quad * 4 + reg;
            float dv = dinv[r];
#pragma unroll
            for (int t = 0; t < 2; t++)
                out[(size_t)r * 128 + nb + t * 16 + nn] = (_Float16)(acc[m][t][reg] * dv);
        }
    }
}

// NC=40 (3 n-tiles, cols padded to 48). Wave owns its own 32-row strip, all cols.
__launch_bounds__(256)
__global__ void k_gemm40(const _Float16* __restrict__ A,
                         const _Float16* __restrict__ Wthi, const _Float16* __restrict__ Wtlo,
                         const float* __restrict__ dinv, _Float16* __restrict__ out) {
    const int lane = threadIdx.x & 63;
    const int wi = threadIdx.x >> 6;
    const int r0 = (blockIdx.x * 4 + wi) * 32;
    const int nn = lane & 15;
    const int kq = (lane >> 4) * 8;

    h8v bh[4][3], bl[4][3];
#pragma unroll
    for (int c = 0; c < 4; c++)
#pragma unroll
        for (int t = 0; t < 3; t++) {
            int off = (t * 16 + nn) * 128 + c * 32 + kq;
            bh[c][t] = *(const h8v*)(Wthi + off);
            bl[c][t] = *(const h8v*)(Wtlo + off);
        }

    f32x4 acc[2][3] = {};
#pragma unroll
    for (int c = 0; c < 4; c++) {
        h8v a[2];
#pragma unroll
        for (int m = 0; m < 2; m++) {
            int rr = min(r0 + m * 16 + nn, N_NODES - 1);
            a[m] = *(const h8v*)(A + (size_t)rr * 128 + c * 32 + kq);
        }
#pragma unroll
        for (int m = 0; m < 2; m++)
#pragma unroll
            for (int t = 0; t < 3; t++) {
                acc[m][t] = __builtin_amdgcn_mfma_f32_16x16x32_f16(a[m], bh[c][t], acc[m][t], 0, 0, 0);
                acc[m][t] = __builtin_amdgcn_mfma_f32_16x16x32_f16(a[m], bl[c][t], acc[m][t], 0, 0, 0);
            }
    }

    const int quad = lane >> 4;
#pragma unroll
    for (int m = 0; m < 2; m++) {
#pragma unroll
        for (int reg = 0; reg < 4; reg++) {
            int r = r0 + m * 16 + quad * 4 + reg;
            if (r < N_NODES) {
                float dv = dinv[r];
#pragma unroll
                for (int t = 0; t < 3; t++) {
                    int col = t * 16 + nn;
                    if (col < 40)
                        out[(size_t)r * 40 + col] = (_Float16)(acc[m][t][reg] * dv);
                }
            }
        }
    }
}

// ---------------- Aggregation (F=128): wave/row; 8-deep gather unroll ----------------

__launch_bounds__(256)
__global__ void k_agg128(const _Float16* __restrict__ hp, const int* __restrict__ rowptr,
                         const int* __restrict__ colidx, const float* __restrict__ dinv,
                         const float* __restrict__ bias, _Float16* __restrict__ outp) {
    const int r = (blockIdx.x * blockDim.x + threadIdx.x) >> 6;
    const int lane = threadIdx.x & 63;
    if (r >= N_NODES) return;
    const int c0 = lane * 2;
    const _Float16* hpc = hp + c0;

    h2v sv = *(const h2v*)(hpc + (size_t)r * 128);
    float ax = (float)sv.x, ay = (float)sv.y;  // self-loop term
    int e = rowptr[r];
    const int e1 = rowptr[r + 1];
    for (; e + 8 <= e1; e += 8) {
        int s0 = colidx[e], s1 = colidx[e + 1], s2 = colidx[e + 2], s3 = colidx[e + 3];
        int s4 = colidx[e + 4], s5 = colidx[e + 5], s6 = colidx[e + 6], s7 = colidx[e + 7];
        h2v v0 = *(const h2v*)(hpc + (size_t)s0 * 128);
        h2v v1 = *(const h2v*)(hpc + (size_t)s1 * 128);
        h2v v2 = *(const h2v*)(hpc + (size_t)s2 * 128);
        h2v v3 = *(const h2v*)(hpc + (size_t)s3 * 128);
        h2v v4 = *(const h2v*)(hpc + (size_t)s4 * 128);
        h2v v5 = *(const h2v*)(hpc + (size_t)s5 * 128);
        h2v v6 = *(const h2v*)(hpc + (size_t)s6 * 128);
        h2v v7 = *(const h2v*)(hpc + (size_t)s7 * 128);
        ax += (((float)v0.x + (float)v1.x) + ((float)v2.x + (float)v3.x)) +
              (((float)v4.x + (float)v5.x) + ((float)v6.x + (float)v7.x));
        ay += (((float)v0.y + (float)v1.y) + ((float)v2.y + (float)v3.y)) +
              (((float)v4.y + (float)v5.y) + ((float)v6.y + (float)v7.y));
    }
    for (; e < e1; e++) {
        int s = colidx[e];
        h2v v = *(const h2v*)(hpc + (size_t)s * 128);
        ax += (float)v.x;
        ay += (float)v.y;
    }
    float dv = dinv[r];
    float2 b = ((const float2*)bias)[lane];
    float ox = fmaxf(fmaf(dv, ax, b.x), 0.f);
    float oy = fmaxf(fmaf(dv, ay, b.y), 0.f);
    h2v o = {(_Float16)ox, (_Float16)oy};
    *(h2v*)(outp + (size_t)r * 128 + c0) = o;
}

// ---------------- Final aggregation (F=40) + fused log_softmax; 8-deep unroll ----------

__launch_bounds__(256)
__global__ void k_agg_out(const _Float16* __restrict__ hp, const int* __restrict__ rowptr,
                          const int* __restrict__ colidx, const float* __restrict__ dinv,
                          float* __restrict__ out) {
    const int r = (blockIdx.x * blockDim.x + threadIdx.x) >> 6;
    const int lane = threadIdx.x & 63;
    if (r >= N_NODES) return;
    const bool act = lane < 40;
    const int cl = act ? lane : 0;
    const _Float16* hpc = hp + cl;

    float acc = act ? (float)hpc[(size_t)r * 40] : 0.f;  // self-loop
    float acc2 = 0.f;
    int e = rowptr[r];
    const int e1 = rowptr[r + 1];
    for (; e + 8 <= e1; e += 8) {
        int s0 = colidx[e], s1 = colidx[e + 1], s2 = colidx[e + 2], s3 = colidx[e + 3];
        int s4 = colidx[e + 4], s5 = colidx[e + 5], s6 = colidx[e + 6], s7 = colidx[e + 7];
        float v0 = (float)hpc[(size_t)s0 * 40];
        float v1 = (float)hpc[(size_t)s1 * 40];
        float v2 = (float)hpc[(size_t)s2 * 40];
        float v3 = (float)hpc[(size_t)s3 * 40];
        float v4 = (float)hpc[(size_t)s4 * 40];
        float v5 = (float)hpc[(size_t)s5 * 40];
        float v6 = (float)hpc[(size_t)s6 * 40];
        float v7 = (float)hpc[(size_t)s7 * 40];
        acc += (v0 + v1) + (v2 + v3);
        acc2 += (v4 + v5) + (v6 + v7);
    }
    for (; e < e1; e++) {
        int s = colidx[e];
        acc += (float)hpc[(size_t)s * 40];
    }
    acc += acc2;
    float z = act ? dinv[r] * acc : -INFINITY;
    float m = z;
    for (int off = 32; off; off >>= 1) m = fmaxf(m, __shfl_xor(m, off));
    float ex = act ? __expf(z - m) : 0.f;
    float se = ex;
    for (int off = 32; off; off >>= 1) se += __shfl_xor(se, off);
    if (act) out[(size_t)r * 40 + lane] = z - m - __logf(se);
}

// ---------------- launch ----------------

extern "C" void kernel_launch(void* const* d_in, const int* in_sizes, int n_in,
                              void* d_out, int out_size, void* d_ws, size_t ws_size,
                              hipStream_t stream) {
    const float* x     = (const float*)d_in[0];
    const int*   ei    = (const int*)d_in[1];
    const float* W_in  = (const float*)d_in[2];
    const float* b_in  = (const float*)d_in[3];
    const float* W_mid = (const float*)d_in[4];
    const float* b_mid = (const float*)d_in[5];
    const float* W_out = (const float*)d_in[6];
    float* out = (float*)d_out;

    const int* srcv = ei;
    const int* dstv = ei + N_EDGES;

    char* w = (char*)d_ws;
    float* dinv   = (float*)(w);                       // 400 KB
    int* rowptr   = (int*)(w + (1ull << 19));          // 400 KB
    int* bcnt     = (int*)(w + (1ull << 20));
    int* bptr     = (int*)(w + (1ull << 20) + 4096);
    int* bcur     = (int*)(w + (1ull << 20) + 8192);
    int* colidx   = (int*)(w + (2ull << 20));          // 6.4 MB
    unsigned int* ebuf = (unsigned int*)(w + (9ull << 20));  // 6.4 MB
    _Float16* Wt1h = (_Float16*)(w + (16ull << 20));
    _Float16* Wt1l = Wt1h + 128 * 128;
    _Float16* Wt2h = Wt1l + 128 * 128;
    _Float16* Wt2l = Wt2h + 128 * 128;
    _Float16* Wt3h = Wt2l + 128 * 128;
    _Float16* Wt3l = Wt3h + 48 * 128;
    _Float16* buf0 = (_Float16*)(w + (18ull << 20));   // 25.6 MB
    _Float16* buf1 = (_Float16*)(w + (46ull << 20));   // 25.6 MB
    _Float16* buf2 = (_Float16*)(w + (74ull << 20));   // 25.6 MB -> ends ~99.6 MB

    const int NB_PART = (N_EDGES + 4095) / 4096;  // 391

    // CSR build (bucketed)
    k_zero_int<<<2, 256, 0, stream>>>(bcnt, 512);
    k_bhist<<<NB_PART, 256, 0, stream>>>(dstv, bcnt);
    k_bscan<<<1, 512, 0, stream>>>(bcnt, bptr, bcur);
    k_bpart<<<NB_PART, 256, 0, stream>>>(srcv, dstv, bcur, ebuf);
    k_brow<<<NBUCK, 256, 0, stream>>>(ebuf, bptr, rowptr, dinv);
    k_bfill<<<NBUCK, 256, 0, stream>>>(ebuf, bptr, rowptr, colidx);

    // weight prep
    k_wprep<<<(128 * 128 + 255) / 256, 256, 0, stream>>>(W_in, 128, 128, Wt1h, Wt1l);
    k_wprep<<<(128 * 128 + 255) / 256, 256, 0, stream>>>(W_mid, 128, 128, Wt2h, Wt2l);
    k_wprep<<<(48 * 128 + 255) / 256, 256, 0, stream>>>(W_out, 40, 48, Wt3h, Wt3l);

    const int AGG_BLOCKS = N_NODES / 4;
    const int GEMM_BLOCKS = N_NODES / 32;

    // Layer 1 (reads fp32 x directly)
    k_gemm128_f32<<<GEMM_BLOCKS, 256, 0, stream>>>(x, Wt1h, Wt1l, dinv, buf1);
    k_agg128<<<AGG_BLOCKS, 256, 0, stream>>>(buf1, rowptr, colidx, dinv, b_in, buf2);
    // Layer 2
    k_gemm128<<<GEMM_BLOCKS, 256, 0, stream>>>(buf2, Wt2h, Wt2l, dinv, buf1);
    k_agg128<<<AGG_BLOCKS, 256, 0, stream>>>(buf1, rowptr, colidx, dinv, b_mid, buf0);
    // Layer 3 + log_softmax
    k_gemm40<<<(N_NODES + 127) / 128, 256, 0, stream>>>(buf0, Wt3h, Wt3l, dinv, buf1);
    k_agg_out<<<AGG_BLOCKS, 256, 0, stream>>>(buf1, rowptr, colidx, dinv, out);
}